// Round 12
// baseline (98.191 us; speedup 1.0000x reference)
//
#include <hip/hip_runtime.h>
#include <math.h>

#define B   8
#define S   256
#define NT  50
#define E   64
#define NTE (NT * E)
#define EPSF 1e-16f

#define NW        16                // waves per block (1024 threads)
#define NTHREADS  (64 * NW)
#define NBLK      256               // == CU count: exactly 1 block per CU
#define PAIRS_PB  4                 // 1024 row-pairs / 256 blocks
#define LL_PAIRS  (B * S / 2)       // 1024
#define IN_TILES  (B * NT)          // 400; tiles bid and bid+256

__device__ __forceinline__ float softplus(float x) {
    if (x > 20.0f) return x;
    return log1pf(__expf(x));
}

__device__ __forceinline__ float wave_reduce_sum(float v) {
    #pragma unroll
    for (int off = 32; off > 0; off >>= 1)
        v += __shfl_down(v, off, 64);
    return v;  // lane 0 holds the sum
}

// ---------------------------------------------------------------------------
// Main kernel. Grid = 256 blocks (1 per CU), 1024 threads (16 waves).
//
// L1-blocking: the inner loops gather A[tyj][tyi][e]/P[tyj][tyi][e] -- for a
// FIXED row tyi that is a 25.6 KB working set (50 types x 2 x 256B), which
// fits the 32 KB L1 with ~5x reuse. Previous kernels ran 4 blocks/CU x 1
// active row = ~102 KB -> L1 thrash -> every gather was an L2 round trip
// (the invariant ~37us main = ~134MB / MSHR-bound ~3.6TB/s). Here exactly
// ONE block per CU processes its 4 row-pairs ROW-SERIALLY (all 16 waves on
// the same row -> one 25.6 KB set resident), then its <=2 integral tiles
// (same reuse structure). TLP: 16 waves/CU = 4/SIMD, unroll-8 ILP on top.
// All 4 pairs of a block share one batch (4 | 128), so events stage once.
// ---------------------------------------------------------------------------
__global__ __launch_bounds__(NTHREADS, 4) void main_kernel(
    const float* __restrict__ times, const int* __restrict__ types,
    const int* __restrict__ Tp,
    const float* __restrict__ emb,  const float* __restrict__ a,
    const float* __restrict__ Amat, const float* __restrict__ Pmat,
    float* __restrict__ ws_ll2, float* __restrict__ ws_int)
{
    const int tid = threadIdx.x;
    const int e   = tid & 63;
    const int w   = tid >> 6;            // 0..15
    const int bid = blockIdx.x;          // 0..255
    const int b   = bid >> 5;            // LL batch (= (bid*4)/128)

    __shared__ __align__(16) float  s_emb[NTE];   // 12.8 KB
    __shared__ __align__(16) float4 s_ev[S];      // 4 KB (t, ty*E, ty*NTE, 0)
    __shared__ float s_part[2][NW][E];            // 8 KB

    {
        const float4* __restrict__ emb4 = (const float4*)emb;
        float4* s4 = (float4*)s_emb;
        for (int idx = tid; idx < NTE / 4; idx += NTHREADS)
            s4[idx] = emb4[idx];
    }
    for (int j = tid; j < S; j += NTHREADS) {
        const int ty = types[b * S + j];
        s_ev[j] = make_float4(times[b * S + j],
                              __int_as_float(ty * E),
                              __int_as_float(ty * NTE), 0.0f);
    }
    __syncthreads();

    // ---- 4 LL row pairs, row-serial (one 25.6KB A/P slice active) --------
    for (int pp = 0; pp < PAIRS_PB; ++pp) {
        const int pair = bid * PAIRS_PB + pp;    // = b*128 + ih
        const int ih   = pair & 127;
        const int rows[2] = { ih, S - 1 - ih };

        #pragma unroll
        for (int r = 0; r < 2; ++r) {
            const int   i     = rows[r];
            const float t_i   = s_ev[i].x;
            const int   col   = __float_as_int(s_ev[i].y) + e;   // tyi*E + e
            const float negEi = -s_emb[col];

            float macc = 0.0f;
            #pragma unroll 8
            for (int j = w; j < i; j += NW) {
                const float4 ev  = s_ev[j];                      // uniform b128
                const float  dtj = t_i - ev.x;
                const int   base = __float_as_int(ev.z) + col;   // tyj*NTE+col
                const float ej   = s_emb[__float_as_int(ev.y) + e];
                const float Pe   = Pmat[base];
                const float Ae   = Amat[base];
                macc = fmaf(Ae * ej, __expf(negEi * Pe * ej * dtj), macc);
            }
            s_part[r][w][e] = macc;
        }
        __syncthreads();
        if (w < 2) {   // one wave per row: reduce partials, write own half
            const int   i     = rows[w];
            const float t_i   = s_ev[i].x;
            const int   col   = __float_as_int(s_ev[i].y) + e;
            const float emb_i = s_emb[col];
            float mt = 0.0f;
            #pragma unroll
            for (int q = 0; q < NW; ++q) mt += s_part[w][q][e];
            const float sp    = softplus(fmaf(emb_i, mt, emb_i * a[col]));
            const float inten = wave_reduce_sum(sp);
            if (e == 0)
                ws_ll2[pair * 2 + w] = (t_i >= 0.0f) ? logf(inten + EPSF) : 0.0f;
        }
        __syncthreads();   // s_part safe to overwrite next pair
    }

    // ---- integral tiles bid and bid+256 (<=2 per block) ------------------
    #pragma unroll
    for (int tt = 0; tt < 2; ++tt) {
        const int t = bid + tt * NBLK;
        if (t >= IN_TILES) break;
        const int b2 = t / NT;
        const int k  = t % NT;

        // restage events for batch b2 (s_emb is batch-independent)
        for (int j = tid; j < S; j += NTHREADS) {
            const int ty = types[b2 * S + j];
            s_ev[j] = make_float4(times[b2 * S + j],
                                  __int_as_float(ty * E),
                                  __int_as_float(ty * NTE), 0.0f);
        }
        __syncthreads();

        const float Tf    = (float)(*Tp);
        const int   colk  = k * E + e;
        const float embk  = s_emb[colk];
        const float negEk = -embk;

        float acc = 0.0f;
        #pragma unroll 8
        for (int i = w; i < S; i += NW) {
            const float4 ev  = s_ev[i];
            const float  dT  = Tf - ev.x;
            const int   base = __float_as_int(ev.z) + colk;
            const float et   = s_emb[__float_as_int(ev.y) + e];
            const float c    = Amat[base] * et * __expf(negEk * Pmat[base] * et * dT);
            acc += (ev.x >= 0.0f) ? c : 0.0f;    // predicated, no branch
        }
        s_part[0][w][e] = acc;
        __syncthreads();
        if (w == 0) {
            float mt = 0.0f;
            #pragma unroll
            for (int q = 0; q < NW; ++q) mt += s_part[0][q][e];
            const float sp = softplus(fmaf(embk, mt, embk * a[colk]));
            const float s  = wave_reduce_sum(sp);
            if (e == 0) ws_int[t] = s;
        }
        __syncthreads();   // protect s_ev restage / s_part reuse
    }
}

// ---------------------------------------------------------------------------
// Finalize: one block, 4 waves. ws_ll2 has 2048 half-row entries.
// ---------------------------------------------------------------------------
__global__ __launch_bounds__(256) void finalize_kernel(
    const float* __restrict__ times,
    const int* __restrict__ Tp,
    const float* __restrict__ emb, const float* __restrict__ a,
    const float* __restrict__ ws_ll2, const float* __restrict__ ws_int,
    float* __restrict__ out)
{
    const int t    = threadIdx.x;
    const int lane = t & 63;
    const int w    = t >> 6;
    const float Tf = (float)(*Tp);

    float llp = 0.0f;
    for (int idx = t; idx < 2 * LL_PAIRS; idx += 256) llp += ws_ll2[idx];
    float bs = 0.0f;
    for (int idx = t; idx < NTE; idx += 256) bs += softplus(emb[idx] * a[idx]);

    __shared__ float red[256], red2[256];
    red[t] = llp; red2[t] = bs;

    __shared__ float s_first[B], s_last[B], s_iT[B], s_any[B];
    for (int b = w; b < B; b += 4) {
        float mn = 1e30f, mx = -1e30f;
        #pragma unroll
        for (int q = 0; q < S / 64; ++q) {
            const float tv = times[b * S + q * 64 + lane];
            const bool valid = (tv >= 0.0f);
            mn = fminf(mn, valid ? tv : 1e30f);
            mx = fmaxf(mx, valid ? tv : -1e30f);
        }
        float iv = (lane < NT) ? ws_int[b * NT + lane] : 0.0f;
        #pragma unroll
        for (int off = 32; off > 0; off >>= 1) {
            mn = fminf(mn, __shfl_down(mn, off, 64));
            mx = fmaxf(mx, __shfl_down(mx, off, 64));
            iv += __shfl_down(iv, off, 64);
        }
        if (lane == 0) {
            const bool any_valid = (mn < 1e29f);
            s_any[b]   = any_valid ? 1.0f : 0.0f;
            s_first[b] = any_valid ? mn : 0.0f;
            s_last[b]  = any_valid ? mx : 0.0f;
            s_iT[b]    = iv;
        }
    }
    __syncthreads();

    for (int off = 128; off > 0; off >>= 1) {
        if (t < off) { red[t] += red[t + off]; red2[t] += red2[t + off]; }
        __syncthreads();
    }

    if (t == 0) {
        const float base_sum = red2[0];
        float integral = 0.0f;
        #pragma unroll
        for (int b = 0; b < B; ++b) {
            integral += (s_any[b] > 0.5f)
                ? s_iT[b] * (Tf - s_last[b]) + base_sum * s_first[b]
                : base_sum * Tf;
        }
        out[0] = integral - red[0];
    }
}

extern "C" void kernel_launch(void* const* d_in, const int* in_sizes, int n_in,
                              void* d_out, int out_size, void* d_ws, size_t ws_size,
                              hipStream_t stream) {
    const float* times = (const float*)d_in[0];
    const int*   types = (const int*)d_in[1];
    const int*   Tp    = (const int*)d_in[2];
    const float* emb   = (const float*)d_in[3];
    const float* a     = (const float*)d_in[4];
    const float* Amat  = (const float*)d_in[5];
    const float* Pmat  = (const float*)d_in[6];

    float* ws      = (float*)d_ws;
    float* ws_ll2  = ws;                     // [0, 2048)
    float* ws_int  = ws + 2 * LL_PAIRS;      // [2048, 2448)
    float* out     = (float*)d_out;

    main_kernel<<<NBLK, NTHREADS, 0, stream>>>(
        times, types, Tp, emb, a, Amat, Pmat, ws_ll2, ws_int);
    finalize_kernel<<<1, 256, 0, stream>>>(times, Tp, emb, a, ws_ll2, ws_int, out);
}

// Round 13
// 89.171 us; speedup vs baseline: 1.1012x; 1.1012x over previous
//
#include <hip/hip_runtime.h>
#include <math.h>

#define B   8
#define S   256
#define NT  50
#define E   64
#define NTE (NT * E)
#define EPSF 1e-16f

#define NW        8                 // waves per block (512 threads)
#define NTHREADS  (64 * NW)
#define LL_BLOCKS (B * S / 2)       // 1024 blocks; each handles rows (ih, S-1-ih)
#define IN_BLOCKS (B * NT)          // 400 blocks

__device__ __forceinline__ float softplus(float x) {
    if (x > 20.0f) return x;
    return log1pf(__expf(x));
}

__device__ __forceinline__ float wave_reduce_sum(float v) {
    #pragma unroll
    for (int off = 32; off > 0; off >>= 1)
        v += __shfl_down(v, off, 64);
    return v;  // lane 0 holds the sum
}

// ---------------------------------------------------------------------------
// Main kernel. Grid = LL_BLOCKS + IN_BLOCKS, 512 threads (8 waves).
// This is the best-measured variant of this session (87.3 us total).
//
// Structure: per-block s_emb (12.8 KB) + packed event records (t, ty*E,
// ty*NTE) in LDS; LL blocks process the balanced row pair (ih, 255-ih) with
// waves splitting the j-loop stride-8; IN blocks process one (b,k) tile.
// Latency-structural floor: per wave-iteration the chain
// ds_read(ev) -> ds_read(ej)/global(A,P) -> exp is ~500 cy; at the 32
// waves/CU occupancy cap the machine interleaves 8 chains/SIMD -> ~62
// cy/wave-iter x ~1420 wave-iters/CU = ~37 us. All structural variants
// (fused table, readlane, SW-pipeline, CSR, L1-blocking, launch fusion)
// measured within +-3 us of this floor; this version is the minimum.
// ---------------------------------------------------------------------------
__global__ __launch_bounds__(NTHREADS, 8) void main_kernel(
    const float* __restrict__ times, const int* __restrict__ types,
    const int* __restrict__ Tp,
    const float* __restrict__ emb,  const float* __restrict__ a,
    const float* __restrict__ Amat, const float* __restrict__ Pmat,
    float* __restrict__ ws_ll, float* __restrict__ ws_int)
{
    const int tid = threadIdx.x;
    const int e   = tid & 63;
    const int w   = tid >> 6;
    const int bid = blockIdx.x;
    const bool is_ll = (bid < LL_BLOCKS);
    const int b = is_ll ? (bid / (S / 2)) : ((bid - LL_BLOCKS) / NT);

    __shared__ __align__(16) float  s_emb[NTE];   // 12.8 KB, lane-contiguous
    __shared__ __align__(16) float4 s_ev[S];      // (t, ty*E, ty*NTE, 0) bits
    __shared__ float s_part[2][NW][E];            // 4 KB
    __shared__ float s_row[2];

    {
        const float4* __restrict__ emb4 = (const float4*)emb;
        float4* s4 = (float4*)s_emb;
        for (int idx = tid; idx < NTE / 4; idx += NTHREADS)
            s4[idx] = emb4[idx];
    }
    for (int j = tid; j < S; j += NTHREADS) {
        const int ty = types[b * S + j];
        s_ev[j] = make_float4(times[b * S + j],
                              __int_as_float(ty * E),
                              __int_as_float(ty * NTE), 0.0f);
    }
    __syncthreads();

    if (is_ll) {
        const int ih = bid % (S / 2);
        const int rows[2] = { ih, S - 1 - ih };
        #pragma unroll
        for (int r = 0; r < 2; ++r) {
            const int   i     = rows[r];
            const float t_i   = s_ev[i].x;
            const int   col   = __float_as_int(s_ev[i].y) + e;   // tyi*E + e
            const float negEi = -s_emb[col];

            float macc = 0.0f;
            #pragma unroll 8
            for (int j = w; j < i; j += NW) {
                const float4 ev  = s_ev[j];                      // uniform b128
                const float  dtj = t_i - ev.x;
                const int   base = __float_as_int(ev.z) + col;   // tyj*NTE+col
                const float ej   = s_emb[__float_as_int(ev.y) + e];
                const float Pe   = Pmat[base];
                const float Ae   = Amat[base];
                macc = fmaf(Ae * ej, __expf(negEi * Pe * ej * dtj), macc);
            }
            s_part[r][w][e] = macc;
        }
        __syncthreads();
        if (w < 2) {
            const int   i     = rows[w];
            const float t_i   = s_ev[i].x;
            const int   col   = __float_as_int(s_ev[i].y) + e;
            const float emb_i = s_emb[col];
            float mt = 0.0f;
            #pragma unroll
            for (int q = 0; q < NW; ++q) mt += s_part[w][q][e];
            const float sp    = softplus(fmaf(emb_i, mt, emb_i * a[col]));
            const float inten = wave_reduce_sum(sp);
            if (e == 0)
                s_row[w] = (t_i >= 0.0f) ? logf(inten + EPSF) : 0.0f;
        }
        __syncthreads();
        if (tid == 0) ws_ll[bid] = s_row[0] + s_row[1];
    } else {
        const int   k     = (bid - LL_BLOCKS) % NT;
        const float Tf    = (float)(*Tp);
        const int   colk  = k * E + e;
        const float embk  = s_emb[colk];
        const float negEk = -embk;

        float acc = 0.0f;
        #pragma unroll 8
        for (int i = w; i < S; i += NW) {
            const float4 ev  = s_ev[i];
            const float  dT  = Tf - ev.x;
            const int   base = __float_as_int(ev.z) + colk;
            const float et   = s_emb[__float_as_int(ev.y) + e];
            const float c    = Amat[base] * et * __expf(negEk * Pmat[base] * et * dT);
            acc += (ev.x >= 0.0f) ? c : 0.0f;   // predicated, no branch
        }
        s_part[0][w][e] = acc;
        __syncthreads();
        if (w == 0) {
            float mt = 0.0f;
            #pragma unroll
            for (int q = 0; q < NW; ++q) mt += s_part[0][q][e];
            const float sp = softplus(fmaf(embk, mt, embk * a[colk]));
            const float s  = wave_reduce_sum(sp);
            if (e == 0) ws_int[bid - LL_BLOCKS] = s;
        }
    }
}

// ---------------------------------------------------------------------------
// Finalize: one block, 4 waves (verified version, unchanged).
// ---------------------------------------------------------------------------
__global__ __launch_bounds__(256) void finalize_kernel(
    const float* __restrict__ times,
    const int* __restrict__ Tp,
    const float* __restrict__ emb, const float* __restrict__ a,
    const float* __restrict__ ws_ll, const float* __restrict__ ws_int,
    float* __restrict__ out)
{
    const int t    = threadIdx.x;
    const int lane = t & 63;
    const int w    = t >> 6;
    const float Tf = (float)(*Tp);

    float llp = 0.0f;
    for (int idx = t; idx < LL_BLOCKS; idx += 256) llp += ws_ll[idx];
    float bs = 0.0f;
    for (int idx = t; idx < NTE; idx += 256) bs += softplus(emb[idx] * a[idx]);

    __shared__ float red[256], red2[256];
    red[t] = llp; red2[t] = bs;

    __shared__ float s_first[B], s_last[B], s_iT[B], s_any[B];
    for (int b = w; b < B; b += 4) {
        float mn = 1e30f, mx = -1e30f;
        #pragma unroll
        for (int q = 0; q < S / 64; ++q) {
            const float tv = times[b * S + q * 64 + lane];
            const bool valid = (tv >= 0.0f);
            mn = fminf(mn, valid ? tv : 1e30f);
            mx = fmaxf(mx, valid ? tv : -1e30f);
        }
        float iv = (lane < NT) ? ws_int[b * NT + lane] : 0.0f;
        #pragma unroll
        for (int off = 32; off > 0; off >>= 1) {
            mn = fminf(mn, __shfl_down(mn, off, 64));
            mx = fmaxf(mx, __shfl_down(mx, off, 64));
            iv += __shfl_down(iv, off, 64);
        }
        if (lane == 0) {
            const bool any_valid = (mn < 1e29f);
            s_any[b]   = any_valid ? 1.0f : 0.0f;
            s_first[b] = any_valid ? mn : 0.0f;
            s_last[b]  = any_valid ? mx : 0.0f;
            s_iT[b]    = iv;
        }
    }
    __syncthreads();

    for (int off = 128; off > 0; off >>= 1) {
        if (t < off) { red[t] += red[t + off]; red2[t] += red2[t + off]; }
        __syncthreads();
    }

    if (t == 0) {
        const float base_sum = red2[0];
        float integral = 0.0f;
        #pragma unroll
        for (int b = 0; b < B; ++b) {
            integral += (s_any[b] > 0.5f)
                ? s_iT[b] * (Tf - s_last[b]) + base_sum * s_first[b]
                : base_sum * Tf;
        }
        out[0] = integral - red[0];
    }
}

extern "C" void kernel_launch(void* const* d_in, const int* in_sizes, int n_in,
                              void* d_out, int out_size, void* d_ws, size_t ws_size,
                              hipStream_t stream) {
    const float* times = (const float*)d_in[0];
    const int*   types = (const int*)d_in[1];
    const int*   Tp    = (const int*)d_in[2];
    const float* emb   = (const float*)d_in[3];
    const float* a     = (const float*)d_in[4];
    const float* Amat  = (const float*)d_in[5];
    const float* Pmat  = (const float*)d_in[6];

    float* ws     = (float*)d_ws;
    float* ws_ll  = ws;                  // [0, 1024)
    float* ws_int = ws + LL_BLOCKS;      // [1024, 1424)
    float* out    = (float*)d_out;

    main_kernel<<<LL_BLOCKS + IN_BLOCKS, NTHREADS, 0, stream>>>(
        times, types, Tp, emb, a, Amat, Pmat, ws_ll, ws_int);
    finalize_kernel<<<1, 256, 0, stream>>>(times, Tp, emb, a, ws_ll, ws_int, out);
}